// Round 1
// baseline (1812.716 us; speedup 1.0000x reference)
//
#include <hip/hip_runtime.h>
#include <math.h>

// SparseMoEALU: B=16384 instruction states, P=8 positions, D=64, H=128, 37 ops.
// One wave (64 lanes) per batch element; lane = channel d; x[8][64] lives in
// 8 VGPRs/lane for the whole pipeline. Wave-uniform branching on opcode masks
// skips dead (masked-off) work: 196 GFLOP reference -> ~22.4 GFLOP actual.

constexpr int NB = 16384;   // batch
constexpr int NP = 8;       // positions
constexpr int ND = 64;      // d_model
constexpr int NH = 128;     // hidden
constexpr int OP_START = 16;
constexpr int NOPS = 37;

// FFN with ReLU + residual: x += relu(x@W1 + b1)@W2 + b2
// W1: [64][128], b1: [128], W2: [128][64], b2: [64]. lane = d (0..63).
__device__ __forceinline__ void ffn_residual(
    float xp[8],
    const float* __restrict__ W1, const float* __restrict__ b1,
    const float* __restrict__ W2, const float* __restrict__ b2, int lane)
{
    float hlo[8], hhi[8];
    const float blo = b1[lane], bhi = b1[lane + 64];
    #pragma unroll
    for (int p = 0; p < 8; ++p) { hlo[p] = blo; hhi[p] = bhi; }

    // h[p][j] = sum_d x[p][d] * W1[d][j]; lane holds j=lane (lo) and j=lane+64 (hi)
    #pragma unroll 4
    for (int d = 0; d < 64; ++d) {
        const float wlo = W1[d * 128 + lane];
        const float whi = W1[d * 128 + lane + 64];
        #pragma unroll
        for (int p = 0; p < 8; ++p) {
            const float xv = __shfl(xp[p], d);
            hlo[p] = fmaf(xv, wlo, hlo[p]);
            hhi[p] = fmaf(xv, whi, hhi[p]);
        }
    }
    #pragma unroll
    for (int p = 0; p < 8; ++p) {
        hlo[p] = fmaxf(hlo[p], 0.0f);
        hhi[p] = fmaxf(hhi[p], 0.0f);
    }

    // out[p][d] = sum_j h[p][j] * W2[j][d]; h[p][j] lives in lane j (lo) / j-64 (hi)
    float acc[8];
    const float bo = b2[lane];
    #pragma unroll
    for (int p = 0; p < 8; ++p) acc[p] = bo;
    #pragma unroll 4
    for (int j = 0; j < 64; ++j) {
        const float w0 = W2[j * 64 + lane];
        const float w1 = W2[(j + 64) * 64 + lane];
        #pragma unroll
        for (int p = 0; p < 8; ++p) {
            acc[p] = fmaf(__shfl(hlo[p], j), w0, acc[p]);
            acc[p] = fmaf(__shfl(hhi[p], j), w1, acc[p]);
        }
    }
    #pragma unroll
    for (int p = 0; p < 8; ++p) xp[p] += acc[p];
}

// Carry attention across the 8 positions, residual. Wq/Wk/Wv: [64][64].
__device__ __forceinline__ void attn_residual(
    float xp[8],
    const float* __restrict__ Wq, const float* __restrict__ Wk,
    const float* __restrict__ Wv, int lane)
{
    float q[8], k[8], v[8];
    #pragma unroll
    for (int p = 0; p < 8; ++p) { q[p] = 0.f; k[p] = 0.f; v[p] = 0.f; }

    #pragma unroll 4
    for (int e = 0; e < 64; ++e) {
        const float wq = Wq[e * 64 + lane];
        const float wk = Wk[e * 64 + lane];
        const float wv = Wv[e * 64 + lane];
        #pragma unroll
        for (int p = 0; p < 8; ++p) {
            const float xv = __shfl(xp[p], e);
            q[p] = fmaf(xv, wq, q[p]);
            k[p] = fmaf(xv, wk, k[p]);
            v[p] = fmaf(xv, wv, v[p]);
        }
    }

    // scores s[p][qq] = sum_d q[p][d]*k[qq][d]; butterfly-reduce 8 dots at once.
    #pragma unroll
    for (int p = 0; p < 8; ++p) {
        float t[8];
        #pragma unroll
        for (int qq = 0; qq < 8; ++qq) t[qq] = q[p] * k[qq];
        #pragma unroll
        for (int s = 1; s < 64; s <<= 1) {
            #pragma unroll
            for (int qq = 0; qq < 8; ++qq) t[qq] += __shfl_xor(t[qq], s);
        }
        // every lane now holds the full row of raw scores; softmax (redundant per lane)
        float m = t[0];
        #pragma unroll
        for (int qq = 1; qq < 8; ++qq) m = fmaxf(m, t[qq]);
        float sum = 0.f;
        #pragma unroll
        for (int qq = 0; qq < 8; ++qq) {
            t[qq] = __expf((t[qq] - m) * 0.125f);   // 1/sqrt(64) scale
            sum += t[qq];
        }
        const float inv = 1.0f / sum;
        #pragma unroll
        for (int qq = 0; qq < 8; ++qq)
            xp[p] = fmaf(t[qq] * inv, v[qq], xp[p]);
    }
}

__global__ void __launch_bounds__(256)
sparse_moe_alu_kernel(
    const float* __restrict__ x,
    const float* __restrict__ Wi1, const float* __restrict__ bi1,
    const float* __restrict__ Wi2, const float* __restrict__ bi2,
    const float* __restrict__ Wq,  const float* __restrict__ Wk,
    const float* __restrict__ Wv,
    const float* __restrict__ Wc1, const float* __restrict__ bc1,
    const float* __restrict__ Wc2, const float* __restrict__ bc2,
    const float* __restrict__ Wd1, const float* __restrict__ bd1,
    const float* __restrict__ Wd2, const float* __restrict__ bd2,
    const float* __restrict__ Wm1, const float* __restrict__ bm1,
    const float* __restrict__ Wm2, const float* __restrict__ bm2,
    const float* __restrict__ Wf1, const float* __restrict__ bf1,
    const float* __restrict__ Wf2, const float* __restrict__ bf2,
    float* __restrict__ out)
{
    const int wave = (blockIdx.x * (int)blockDim.x + (int)threadIdx.x) >> 6;
    const int lane = threadIdx.x & 63;
    if (wave >= NB) return;

    const float* xb = x + (size_t)wave * (NP * ND);
    float xp[8];
    #pragma unroll
    for (int p = 0; p < 8; ++p) xp[p] = xb[p * ND + lane];

    // opcode = argmax over x[b,0,16:53]; tie-break lowest index (jnp.argmax semantics)
    float av = (lane >= OP_START && lane < OP_START + NOPS) ? xp[0] : -INFINITY;
    int ai = lane;
    #pragma unroll
    for (int s = 1; s < 64; s <<= 1) {
        const float ov = __shfl_xor(av, s);
        const int   oi = __shfl_xor(ai, s);
        if (ov > av || (ov == av && oi < ai)) { av = ov; ai = oi; }
    }
    const int op = ai - OP_START;

    // Stage 1: initial opcode-routed expert FFN (all rows)
    ffn_residual(xp, Wi1 + (size_t)op * ND * NH, bi1 + op * NH,
                     Wi2 + (size_t)op * NH * ND, bi2 + op * ND, lane);

    // Stages 2-3: 7x (attention + carry expert), only for carry ops {0,1,2,10..13}
    const bool carry = (op <= 2) || (op >= 10 && op <= 13);
    if (carry) {
        for (int it = 0; it < 7; ++it) {
            attn_residual(xp, Wq, Wk, Wv, lane);
            ffn_residual(xp, Wc1 + (size_t)op * ND * NH, bc1 + op * NH,
                             Wc2 + (size_t)op * NH * ND, bc2 + op * ND, lane);
        }
    }

    // 16 iterative DIV FFNs (op==3) / MOD FFNs (op==4)
    if (op == 3) {
        for (int i = 0; i < 16; ++i)
            ffn_residual(xp, Wd1 + (size_t)i * ND * NH, bd1 + i * NH,
                             Wd2 + (size_t)i * NH * ND, bd2 + i * ND, lane);
    }
    if (op == 4) {
        for (int i = 0; i < 16; ++i)
            ffn_residual(xp, Wm1 + (size_t)i * ND * NH, bm1 + i * NH,
                             Wm2 + (size_t)i * NH * ND, bm2 + i * ND, lane);
    }

    // Stage 4: finalization experts (all rows)
    ffn_residual(xp, Wf1 + (size_t)op * ND * NH, bf1 + op * NH,
                     Wf2 + (size_t)op * NH * ND, bf2 + op * ND, lane);

    float* ob = out + (size_t)wave * (NP * ND);
    #pragma unroll
    for (int p = 0; p < 8; ++p) ob[p * ND + lane] = xp[p];
}

extern "C" void kernel_launch(void* const* d_in, const int* in_sizes, int n_in,
                              void* d_out, int out_size, void* d_ws, size_t ws_size,
                              hipStream_t stream) {
    const float* x   = (const float*)d_in[0];
    const float* Wi1 = (const float*)d_in[1];
    const float* bi1 = (const float*)d_in[2];
    const float* Wi2 = (const float*)d_in[3];
    const float* bi2 = (const float*)d_in[4];
    const float* Wq  = (const float*)d_in[5];
    const float* Wk  = (const float*)d_in[6];
    const float* Wv  = (const float*)d_in[7];
    const float* Wc1 = (const float*)d_in[8];
    const float* bc1 = (const float*)d_in[9];
    const float* Wc2 = (const float*)d_in[10];
    const float* bc2 = (const float*)d_in[11];
    const float* Wd1 = (const float*)d_in[12];
    const float* bd1 = (const float*)d_in[13];
    const float* Wd2 = (const float*)d_in[14];
    const float* bd2 = (const float*)d_in[15];
    const float* Wm1 = (const float*)d_in[16];
    const float* bm1 = (const float*)d_in[17];
    const float* Wm2 = (const float*)d_in[18];
    const float* bm2 = (const float*)d_in[19];
    const float* Wf1 = (const float*)d_in[20];
    const float* bf1 = (const float*)d_in[21];
    const float* Wf2 = (const float*)d_in[22];
    const float* bf2 = (const float*)d_in[23];
    float* out = (float*)d_out;

    const int threads = 256;                 // 4 waves/block, 1 wave per batch row
    const int blocks  = NB / 4;              // 16384 waves total
    sparse_moe_alu_kernel<<<blocks, threads, 0, stream>>>(
        x, Wi1, bi1, Wi2, bi2, Wq, Wk, Wv, Wc1, bc1, Wc2, bc2,
        Wd1, bd1, Wd2, bd2, Wm1, bm1, Wm2, bm2, Wf1, bf1, Wf2, bf2, out);
}

// Round 2
// 329.572 us; speedup vs baseline: 5.5002x; 5.5002x over previous
//
#include <hip/hip_runtime.h>
#include <math.h>

// SparseMoEALU via MFMA: bucket 16384 rows by opcode, then 1 wave per 4
// same-op rows (M=32). X state fp32 in LDS; FFN/attention as bf16 MFMA
// GEMMs with fp32 accumulate; weights pre-transposed to bf16 [N][K] in ws.

typedef __bf16 bfrag __attribute__((ext_vector_type(8)));
typedef float f32x4 __attribute__((ext_vector_type(4)));

#define MFMA16(a,b,c) __builtin_amdgcn_mfma_f32_16x16x32_bf16((a),(b),(c),0,0,0)

constexpr int NB = 16384, NOPS = 37, OP_START = 16;

// ws layout (int32 units for the bucketing region)
constexpr int WS_OPARR  = 0;
constexpr int WS_CNT    = 16384;
constexpr int WS_OFF    = 16448;   // 38 ints
constexpr int WS_CUR    = 16512;
constexpr int WS_ROWIDX = 16640;
constexpr int WS_INTS   = 33024;   // -> weight region at byte 132096

// bf16 element offsets inside weight region
constexpr int OFF_QKVT = 0;        // [192][64]
constexpr int OFF_WI1T = 12288;    // 37 x [128][64]
constexpr int OFF_WI2T = 315392;   // 37 x [64][128]
constexpr int OFF_WC1T = 618496;
constexpr int OFF_WC2T = 921600;
constexpr int OFF_WF1T = 1224704;
constexpr int OFF_WF2T = 1527808;
constexpr int OFF_WD1T = 1830912;  // 16 x [128][64]
constexpr int OFF_WD2T = 1961984;  // 16 x [64][128]
constexpr int OFF_WM1T = 2093056;
constexpr int OFF_WM2T = 2224128;

// ---------------- prep kernels ----------------

__global__ void k_zero(int* cnt, int* cur) {
    int t = threadIdx.x;
    if (t < NOPS) { cnt[t] = 0; cur[t] = 0; }
}

__global__ void k_op(const float* __restrict__ x, int* __restrict__ opArr, int* __restrict__ cnt) {
    int b = blockIdx.x * 256 + threadIdx.x;
    if (b >= NB) return;
    const float* p = x + (size_t)b * 512 + OP_START;
    float best = p[0]; int op = 0;
    for (int j = 1; j < NOPS; ++j) { float v = p[j]; if (v > best) { best = v; op = j; } }
    opArr[b] = op;
    atomicAdd(&cnt[op], 1);
}

__global__ void k_scan(const int* __restrict__ cnt, int* __restrict__ off) {
    if (threadIdx.x == 0) {
        int a = 0;
        for (int o = 0; o < NOPS; ++o) { off[o] = a; a += cnt[o]; }
        off[NOPS] = a;
    }
}

__global__ void k_scatter(const int* __restrict__ opArr, const int* __restrict__ off,
                          int* __restrict__ cur, int* __restrict__ rowIdx) {
    int b = blockIdx.x * 256 + threadIdx.x;
    if (b >= NB) return;
    int op = opArr[b];
    int pos = off[op] + atomicAdd(&cur[op], 1);
    rowIdx[pos] = b;
}

// transpose one [R][C] fp32 matrix -> [C][R] bf16 (289 blocks)
__global__ void k_wt(const float* __restrict__ Wi1, const float* __restrict__ Wi2,
                     const float* __restrict__ Wq,  const float* __restrict__ Wk,
                     const float* __restrict__ Wv,
                     const float* __restrict__ Wc1, const float* __restrict__ Wc2,
                     const float* __restrict__ Wd1, const float* __restrict__ Wd2,
                     const float* __restrict__ Wm1, const float* __restrict__ Wm2,
                     const float* __restrict__ Wf1, const float* __restrict__ Wf2,
                     __bf16* __restrict__ wb) {
    __shared__ float t[8320];  // max R*(C+1) = 128*65
    int m = blockIdx.x;
    const float* src; __bf16* dst; int R, C;
    if      (m < 37)  { src = Wi1 + m * 8192;        dst = wb + OFF_WI1T + m * 8192;        R = 64;  C = 128; }
    else if (m < 74)  { src = Wi2 + (m-37) * 8192;   dst = wb + OFF_WI2T + (m-37) * 8192;   R = 128; C = 64;  }
    else if (m < 111) { src = Wc1 + (m-74) * 8192;   dst = wb + OFF_WC1T + (m-74) * 8192;   R = 64;  C = 128; }
    else if (m < 148) { src = Wc2 + (m-111) * 8192;  dst = wb + OFF_WC2T + (m-111) * 8192;  R = 128; C = 64;  }
    else if (m < 185) { src = Wf1 + (m-148) * 8192;  dst = wb + OFF_WF1T + (m-148) * 8192;  R = 64;  C = 128; }
    else if (m < 222) { src = Wf2 + (m-185) * 8192;  dst = wb + OFF_WF2T + (m-185) * 8192;  R = 128; C = 64;  }
    else if (m < 238) { src = Wd1 + (m-222) * 8192;  dst = wb + OFF_WD1T + (m-222) * 8192;  R = 64;  C = 128; }
    else if (m < 254) { src = Wd2 + (m-238) * 8192;  dst = wb + OFF_WD2T + (m-238) * 8192;  R = 128; C = 64;  }
    else if (m < 270) { src = Wm1 + (m-254) * 8192;  dst = wb + OFF_WM1T + (m-254) * 8192;  R = 64;  C = 128; }
    else if (m < 286) { src = Wm2 + (m-270) * 8192;  dst = wb + OFF_WM2T + (m-270) * 8192;  R = 128; C = 64;  }
    else { const float* q3[3] = {Wq, Wk, Wv}; src = q3[m-286]; dst = wb + OFF_QKVT + (m-286) * 4096; R = 64; C = 64; }
    int n = R * C, Cp = C + 1;
    int logC = (C == 128) ? 7 : 6, logR = (R == 128) ? 7 : 6;
    for (int i = threadIdx.x; i < n; i += 256)
        t[(i >> logC) * Cp + (i & (C - 1))] = src[i];
    __syncthreads();
    for (int o = threadIdx.x; o < n; o += 256) {
        int c = o >> logR, r = o & (R - 1);
        dst[o] = (__bf16)t[r * Cp + c];
    }
}

// ---------------- main kernel helpers ----------------

__device__ __forceinline__ bfrag cvt8(const float* p) {
    float4 a = *(const float4*)p;
    float4 b = *(const float4*)(p + 4);
    bfrag r;
    r[0] = (__bf16)a.x; r[1] = (__bf16)a.y; r[2] = (__bf16)a.z; r[3] = (__bf16)a.w;
    r[4] = (__bf16)b.x; r[5] = (__bf16)b.y; r[6] = (__bf16)b.z; r[7] = (__bf16)b.w;
    return r;
}

__device__ __forceinline__ bfrag zfrag() {
    bfrag r;
    #pragma unroll
    for (int j = 0; j < 8; ++j) r[j] = (__bf16)0.0f;
    return r;
}

// x[32 rows][64] += relu(x@W1+b1)@W2 + b2 ; W1t=[128][64] bf16, W2t=[64][128] bf16
__device__ __forceinline__ void ffn_mfma(float* Xs, __bf16* Hs,
    const __bf16* __restrict__ W1t, const float* __restrict__ b1,
    const __bf16* __restrict__ W2t, const float* __restrict__ b2, int lq, int qd) {
    __syncthreads();
    bfrag a[2][2];
    #pragma unroll
    for (int mt = 0; mt < 2; ++mt)
        #pragma unroll
        for (int kf = 0; kf < 2; ++kf)
            a[mt][kf] = cvt8(&Xs[(mt * 16 + lq) * 68 + kf * 32 + qd * 8]);
    #pragma unroll
    for (int nt = 0; nt < 8; ++nt) {
        float bv = b1[nt * 16 + lq];
        f32x4 acc0 = {bv, bv, bv, bv}, acc1 = acc0;
        #pragma unroll
        for (int kf = 0; kf < 2; ++kf) {
            bfrag w = *(const bfrag*)(W1t + (nt * 16 + lq) * 64 + kf * 32 + qd * 8);
            acc0 = MFMA16(a[0][kf], w, acc0);
            acc1 = MFMA16(a[1][kf], w, acc1);
        }
        #pragma unroll
        for (int r = 0; r < 4; ++r) {
            Hs[(qd * 4 + r) * 136 + nt * 16 + lq]        = (__bf16)fmaxf(acc0[r], 0.0f);
            Hs[(16 + qd * 4 + r) * 136 + nt * 16 + lq]   = (__bf16)fmaxf(acc1[r], 0.0f);
        }
    }
    __syncthreads();
    bfrag a2[2][4];
    #pragma unroll
    for (int mt = 0; mt < 2; ++mt)
        #pragma unroll
        for (int kf = 0; kf < 4; ++kf)
            a2[mt][kf] = *(const bfrag*)&Hs[(mt * 16 + lq) * 136 + kf * 32 + qd * 8];
    #pragma unroll
    for (int nt = 0; nt < 4; ++nt) {
        float bv = b2[nt * 16 + lq];
        f32x4 acc0 = {bv, bv, bv, bv}, acc1 = acc0;
        #pragma unroll
        for (int kf = 0; kf < 4; ++kf) {
            bfrag w = *(const bfrag*)(W2t + (nt * 16 + lq) * 128 + kf * 32 + qd * 8);
            acc0 = MFMA16(a2[0][kf], w, acc0);
            acc1 = MFMA16(a2[1][kf], w, acc1);
        }
        #pragma unroll
        for (int r = 0; r < 4; ++r) {
            Xs[(qd * 4 + r) * 68 + nt * 16 + lq]      += acc0[r];
            Xs[(16 + qd * 4 + r) * 68 + nt * 16 + lq] += acc1[r];
        }
    }
    __syncthreads();
}

// residual attention over the 8 positions of each row; processes 2 chunks of 2 row-slots
__device__ __forceinline__ void attn_mfma(float* Xs, __bf16* Qb, __bf16* Kb, __bf16* Vt,
    float* Sf, __bf16* Pb, const __bf16* __restrict__ qkvt, int lq, int qd) {
    int lane = qd * 16 + lq;
    for (int c = 0; c < 2; ++c) {
        __syncthreads();
        // QKV projection for 16 M-rows (2 row-slots)
        bfrag a[2];
        #pragma unroll
        for (int kf = 0; kf < 2; ++kf)
            a[kf] = cvt8(&Xs[(c * 16 + lq) * 68 + kf * 32 + qd * 8]);
        #pragma unroll
        for (int nt = 0; nt < 12; ++nt) {
            f32x4 acc = {0.f, 0.f, 0.f, 0.f};
            #pragma unroll
            for (int kf = 0; kf < 2; ++kf) {
                bfrag w = *(const bfrag*)(qkvt + (nt * 16 + lq) * 64 + kf * 32 + qd * 8);
                acc = MFMA16(a[kf], w, acc);
            }
            if (nt < 4) {
                #pragma unroll
                for (int r = 0; r < 4; ++r)
                    Qb[(qd * 4 + r) * 72 + nt * 16 + lq] = (__bf16)acc[r];
            } else if (nt < 8) {
                #pragma unroll
                for (int r = 0; r < 4; ++r)
                    Kb[(qd * 4 + r) * 72 + (nt - 4) * 16 + lq] = (__bf16)acc[r];
            } else {
                #pragma unroll
                for (int r = 0; r < 4; ++r) {
                    int m = qd * 4 + r;
                    Vt[((m >> 3) * 64 + (nt - 8) * 16 + lq) * 8 + (m & 7)] = (__bf16)acc[r];
                }
            }
        }
        __syncthreads();
        // scores S = Q K^T * 1/8 per slot
        #pragma unroll
        for (int sl = 0; sl < 2; ++sl) {
            f32x4 acc = {0.f, 0.f, 0.f, 0.f};
            #pragma unroll
            for (int kf = 0; kf < 2; ++kf) {
                bfrag qa = *(const bfrag*)&Qb[(sl * 8 + lq) * 72 + kf * 32 + qd * 8];
                bfrag kb = *(const bfrag*)&Kb[(sl * 8 + lq) * 72 + kf * 32 + qd * 8];
                acc = MFMA16(qa, kb, acc);
            }
            if (qd < 2 && lq < 8) {
                #pragma unroll
                for (int r = 0; r < 4; ++r)
                    Sf[(sl * 8 + qd * 4 + r) * 8 + lq] = acc[r] * 0.125f;
            }
        }
        __syncthreads();
        // softmax (lanes 0..15), zero-pad P rows 8..15 (lanes 16..31)
        if (lane < 16) {
            int sl = lane >> 3, p = lane & 7;
            const float* sp = &Sf[(sl * 8 + p) * 8];
            float t[8];
            #pragma unroll
            for (int j = 0; j < 8; ++j) t[j] = sp[j];
            float mx = t[0];
            #pragma unroll
            for (int j = 1; j < 8; ++j) mx = fmaxf(mx, t[j]);
            float sum = 0.f;
            #pragma unroll
            for (int j = 0; j < 8; ++j) { t[j] = __expf(t[j] - mx); sum += t[j]; }
            float inv = 1.0f / sum;
            bfrag pv;
            #pragma unroll
            for (int j = 0; j < 8; ++j) pv[j] = (__bf16)(t[j] * inv);
            *(bfrag*)&Pb[(sl * 16 + p) * 8] = pv;
        } else if (lane < 32) {
            int l2 = lane - 16, sl = l2 >> 3, p = 8 + (l2 & 7);
            *(bfrag*)&Pb[(sl * 16 + p) * 8] = zfrag();
        }
        __syncthreads();
        // out += P @ V
        #pragma unroll
        for (int sl = 0; sl < 2; ++sl) {
            bfrag pa = zfrag();
            if (qd == 0) pa = *(const bfrag*)&Pb[(sl * 16 + lq) * 8];
            #pragma unroll
            for (int nt = 0; nt < 4; ++nt) {
                bfrag vb = zfrag();
                if (qd == 0) vb = *(const bfrag*)&Vt[(sl * 64 + nt * 16 + lq) * 8];
                f32x4 acc = {0.f, 0.f, 0.f, 0.f};
                acc = MFMA16(pa, vb, acc);
                if (qd < 2) {
                    #pragma unroll
                    for (int r = 0; r < 4; ++r)
                        Xs[(c * 16 + sl * 8 + qd * 4 + r) * 68 + nt * 16 + lq] += acc[r];
                }
            }
        }
        __syncthreads();
    }
}

// ---------------- main kernel ----------------

__global__ void __launch_bounds__(64, 2)
moe_main(const float* __restrict__ x, float* __restrict__ out,
         const int* __restrict__ cnt, const int* __restrict__ off,
         const int* __restrict__ rowIdx, const __bf16* __restrict__ wb,
         const float* __restrict__ bi1, const float* __restrict__ bi2,
         const float* __restrict__ bc1, const float* __restrict__ bc2,
         const float* __restrict__ bd1, const float* __restrict__ bd2,
         const float* __restrict__ bm1, const float* __restrict__ bm2,
         const float* __restrict__ bf1_, const float* __restrict__ bf2_) {
    __shared__ float Xs[32 * 68];                  // 8704 B, stride 68 kills bank conflicts
    __shared__ __align__(16) unsigned char UB[9984];
    __bf16* Hs = (__bf16*)UB;                      // [32][136] (FFN phase)
    __bf16* Qb = (__bf16*)UB;                      // [24][72]  (attn phase, overlaps Hs)
    __bf16* Kb = (__bf16*)(UB + 3456);             // [24][72]
    __bf16* Vt = (__bf16*)(UB + 6912);             // [2][64][8]
    float*  Sf = (float*)(UB + 8960);              // [2][8][8]
    __bf16* Pb = (__bf16*)(UB + 9472);             // [2][16][8]

    int g = blockIdx.x;
    int lane = threadIdx.x, lq = lane & 15, qd = lane >> 4;

    // locate (op, tile) from bucket counts
    int op = -1, tile = 0, acc_ = 0;
    for (int o = 0; o < NOPS; ++o) {
        int t = (cnt[o] + 3) >> 2;
        if (g < acc_ + t) { op = o; tile = g - acc_; break; }
        acc_ += t;
    }
    if (op < 0) return;
    int base = off[op] + tile * 4;
    int nr = cnt[op] - tile * 4; if (nr > 4) nr = 4;
    int rows[4];
    #pragma unroll
    for (int s = 0; s < 4; ++s) rows[s] = rowIdx[base + (s < nr ? s : nr - 1)];

    // load X (4 rows x 8 pos x 64 ch)
    for (int i = lane; i < 2048; i += 64) {
        int m = i >> 6, d = i & 63;
        Xs[m * 68 + d] = x[(size_t)rows[m >> 3] * 512 + (m & 7) * 64 + d];
    }

    // Stage 1: initial experts
    ffn_mfma(Xs, Hs, wb + OFF_WI1T + op * 8192, bi1 + op * 128,
                     wb + OFF_WI2T + op * 8192, bi2 + op * 64, lq, qd);

    // Stages 2-3: carry cascade
    bool carry = (op <= 2) || (op >= 10 && op <= 13);
    if (carry) {
        const __bf16* qkvt = wb + OFF_QKVT;
        for (int it = 0; it < 7; ++it) {
            attn_mfma(Xs, Qb, Kb, Vt, Sf, Pb, qkvt, lq, qd);
            ffn_mfma(Xs, Hs, wb + OFF_WC1T + op * 8192, bc1 + op * 128,
                             wb + OFF_WC2T + op * 8192, bc2 + op * 64, lq, qd);
        }
    }
    // DIV / MOD iterative FFNs
    if (op == 3) {
        for (int i = 0; i < 16; ++i)
            ffn_mfma(Xs, Hs, wb + OFF_WD1T + i * 8192, bd1 + i * 128,
                             wb + OFF_WD2T + i * 8192, bd2 + i * 64, lq, qd);
    }
    if (op == 4) {
        for (int i = 0; i < 16; ++i)
            ffn_mfma(Xs, Hs, wb + OFF_WM1T + i * 8192, bm1 + i * 128,
                             wb + OFF_WM2T + i * 8192, bm2 + i * 64, lq, qd);
    }
    // Stage 4: final experts
    ffn_mfma(Xs, Hs, wb + OFF_WF1T + op * 8192, bf1_ + op * 128,
                     wb + OFF_WF2T + op * 8192, bf2_ + op * 64, lq, qd);

    __syncthreads();
    for (int i = lane; i < nr * 512; i += 64) {
        int s = i >> 9, rem = i & 511;
        out[(size_t)rows[s] * 512 + rem] = Xs[(s * 8 + (rem >> 6)) * 68 + (rem & 63)];
    }
}

// ---------------- launch ----------------

extern "C" void kernel_launch(void* const* d_in, const int* in_sizes, int n_in,
                              void* d_out, int out_size, void* d_ws, size_t ws_size,
                              hipStream_t stream) {
    (void)in_sizes; (void)n_in; (void)out_size; (void)ws_size;
    const float* x   = (const float*)d_in[0];
    const float* Wi1 = (const float*)d_in[1];
    const float* bi1 = (const float*)d_in[2];
    const float* Wi2 = (const float*)d_in[3];
    const float* bi2 = (const float*)d_in[4];
    const float* Wq  = (const float*)d_in[5];
    const float* Wk  = (const float*)d_in[6];
    const float* Wv  = (const float*)d_in[7];
    const float* Wc1 = (const float*)d_in[8];
    const float* bc1 = (const float*)d_in[9];
    const float* Wc2 = (const float*)d_in[10];
    const float* bc2 = (const float*)d_in[11];
    const float* Wd1 = (const float*)d_in[12];
    const float* bd1 = (const float*)d_in[13];
    const float* Wd2 = (const float*)d_in[14];
    const float* bd2 = (const float*)d_in[15];
    const float* Wm1 = (const float*)d_in[16];
    const float* bm1 = (const float*)d_in[17];
    const float* Wm2 = (const float*)d_in[18];
    const float* bm2 = (const float*)d_in[19];
    const float* Wf1 = (const float*)d_in[20];
    const float* bf1 = (const float*)d_in[21];
    const float* Wf2 = (const float*)d_in[22];
    const float* bf2 = (const float*)d_in[23];
    float* out = (float*)d_out;

    int* wsi    = (int*)d_ws;
    int* opArr  = wsi + WS_OPARR;
    int* cnt    = wsi + WS_CNT;
    int* off    = wsi + WS_OFF;
    int* cur    = wsi + WS_CUR;
    int* rowIdx = wsi + WS_ROWIDX;
    __bf16* wb  = (__bf16*)((char*)d_ws + WS_INTS * 4);

    k_zero<<<1, 64, 0, stream>>>(cnt, cur);
    k_op<<<NB / 256, 256, 0, stream>>>(x, opArr, cnt);
    k_scan<<<1, 64, 0, stream>>>(cnt, off);
    k_scatter<<<NB / 256, 256, 0, stream>>>(opArr, off, cur, rowIdx);
    k_wt<<<289, 256, 0, stream>>>(Wi1, Wi2, Wq, Wk, Wv, Wc1, Wc2, Wd1, Wd2, Wm1, Wm2, Wf1, Wf2, wb);
    moe_main<<<NB / 4 + NOPS, 64, 0, stream>>>(x, out, cnt, off, rowIdx, wb,
                                               bi1, bi2, bc1, bc2, bd1, bd2, bm1, bm2, bf1, bf2);
}